// Round 6
// baseline (318.402 us; speedup 1.0000x reference)
//
#include <hip/hip_runtime.h>
#include <hip/hip_bf16.h>

#define B_SEG 16384
#define R_EDGE 262144
#define DKDIM 512
#define DOUT 512

typedef __attribute__((ext_vector_type(4))) float f32x4;
typedef __attribute__((ext_vector_type(8))) short bf16x8;

static __device__ __forceinline__ unsigned short f2bf(float f) {
    union { float f; unsigned int u; } v; v.f = f;
    unsigned int r = (v.u + 0x7FFFu + ((v.u >> 16) & 1u)) >> 16;
    return (unsigned short)r;
}

static __device__ __forceinline__ float dot8(const float4 qa, const float4 qb,
                                             const float4 ka, const float4 kb) {
    return qa.x * ka.x + qa.y * ka.y + qa.z * ka.z + qa.w * ka.w
         + qb.x * kb.x + qb.y * kb.y + qb.z * kb.z + qb.w * kb.w;
}

// ---------------- Stage 0: prep = starts scatter + W_o transpose (fused) -----
// Blocks 0..1023: starts[b] = lower_bound(td, b) via parallel scatter.
// Blocks 1024..1087: 64x64 LDS tile transpose of W_o into bf16 Wt (n-major).
__global__ __launch_bounds__(256) void prep_kernel(
    const int* __restrict__ td, int* __restrict__ starts,
    const float* __restrict__ W, unsigned short* __restrict__ Wt)
{
    if (blockIdx.x < 1024) {
        const int e = blockIdx.x * 256 + threadIdx.x;
        const int cur  = td[e];
        const int prev = (e == 0) ? -1 : td[e - 1];
        for (int b = prev + 1; b <= cur; ++b) starts[b] = e;
        if (e == R_EDGE - 1)
            for (int b = cur + 1; b <= B_SEG; ++b) starts[b] = R_EDGE;
    } else {
        __shared__ unsigned short tile[64][68];
        const int bb = blockIdx.x - 1024;
        const int n0 = (bb & 7) * 64;
        const int k0 = (bb >> 3) * 64;
        const int tx = threadIdx.x & 63, g = threadIdx.x >> 6;  // g in 0..3
        #pragma unroll
        for (int dy = 0; dy < 16; ++dy) {
            const int k = g * 16 + dy;
            tile[tx][k] = f2bf(W[(size_t)(k0 + k) * DOUT + n0 + tx]);  // coalesced
        }
        __syncthreads();
        #pragma unroll
        for (int dr = 0; dr < 16; ++dr) {
            const int r = g * 16 + dr;
            Wt[(size_t)(n0 + r) * DKDIM + k0 + tx] = tile[r][tx];      // coalesced
        }
    }
}

// ---------------- Stage 1: fused segment attention ---------------------------
// ONE SEGMENT = ONE 64-THREAD BLOCK (wave-level load balance). Online softmax;
// K read exactly once from HBM. Segment bounds from the starts table.
__global__ __launch_bounds__(64, 4) void attn_kernel(
    const float* __restrict__ Q, const float* __restrict__ K,
    const int* __restrict__ starts, unsigned short* __restrict__ ctxb)
{
    const int lane = threadIdx.x & 63;
    const int b = blockIdx.x;

    const int s0 = starts[b];
    const int s1 = starts[b + 1];

    // Q row: lane holds elems [4*lane .. 4*lane+3] and [256+4*lane .. +3]
    const float4* Q4 = (const float4*)(Q + (size_t)b * DKDIM);
    const float4 qa = Q4[lane];
    const float4 qb = Q4[64 + lane];

    float m = -INFINITY, l = 0.0f;
    float c0 = 0.f, c1 = 0.f, c2 = 0.f, c3 = 0.f;
    float c4 = 0.f, c5 = 0.f, c6 = 0.f, c7 = 0.f;

    float4 ka0, kb0, ka1, kb1, ka2, kb2, ka3, kb3;

#define LOAD4(dst_a0, dst_b0, dst_a1, dst_b1, dst_a2, dst_b2, dst_a3, dst_b3, ee)            \
    {                                                                                        \
        const float4* K0_ = (const float4*)(K + (size_t)((ee) + 0) * DKDIM);                 \
        const float4* K1_ = (const float4*)(K + (size_t)((ee) + 1) * DKDIM);                 \
        const float4* K2_ = (const float4*)(K + (size_t)((ee) + 2) * DKDIM);                 \
        const float4* K3_ = (const float4*)(K + (size_t)((ee) + 3) * DKDIM);                 \
        dst_a0 = K0_[lane]; dst_b0 = K0_[64 + lane];                                         \
        dst_a1 = K1_[lane]; dst_b1 = K1_[64 + lane];                                         \
        dst_a2 = K2_[lane]; dst_b2 = K2_[64 + lane];                                         \
        dst_a3 = K3_[lane]; dst_b3 = K3_[64 + lane];                                         \
    }

#define PROC4()                                                                              \
    {                                                                                        \
        float p0 = dot8(qa, qb, ka0, kb0);                                                   \
        float p1 = dot8(qa, qb, ka1, kb1);                                                   \
        float p2 = dot8(qa, qb, ka2, kb2);                                                   \
        float p3 = dot8(qa, qb, ka3, kb3);                                                   \
        _Pragma("unroll")                                                                    \
        for (int off = 32; off >= 1; off >>= 1) {                                            \
            p0 += __shfl_xor(p0, off, 64);                                                   \
            p1 += __shfl_xor(p1, off, 64);                                                   \
            p2 += __shfl_xor(p2, off, 64);                                                   \
            p3 += __shfl_xor(p3, off, 64);                                                   \
        }                                                                                    \
        const float nm = fmaxf(fmaxf(fmaxf(p0, p1), fmaxf(p2, p3)), m);                      \
        const float sc = __expf(m - nm);                                                     \
        const float w0 = __expf(p0 - nm), w1 = __expf(p1 - nm);                              \
        const float w2 = __expf(p2 - nm), w3 = __expf(p3 - nm);                              \
        l = l * sc + ((w0 + w1) + (w2 + w3));                                                \
        c0 = c0 * sc + (w0 * ka0.x + w1 * ka1.x) + (w2 * ka2.x + w3 * ka3.x);                \
        c1 = c1 * sc + (w0 * ka0.y + w1 * ka1.y) + (w2 * ka2.y + w3 * ka3.y);                \
        c2 = c2 * sc + (w0 * ka0.z + w1 * ka1.z) + (w2 * ka2.z + w3 * ka3.z);                \
        c3 = c3 * sc + (w0 * ka0.w + w1 * ka1.w) + (w2 * ka2.w + w3 * ka3.w);                \
        c4 = c4 * sc + (w0 * kb0.x + w1 * kb1.x) + (w2 * kb2.x + w3 * kb3.x);                \
        c5 = c5 * sc + (w0 * kb0.y + w1 * kb1.y) + (w2 * kb2.y + w3 * kb3.y);                \
        c6 = c6 * sc + (w0 * kb0.z + w1 * kb1.z) + (w2 * kb2.z + w3 * kb3.z);                \
        c7 = c7 * sc + (w0 * kb0.w + w1 * kb1.w) + (w2 * kb2.w + w3 * kb3.w);                \
        m = nm;                                                                              \
    }

    int e = s0;
    if (s1 - s0 >= 4) {
        LOAD4(ka0, kb0, ka1, kb1, ka2, kb2, ka3, kb3, e);
        for (; e + 7 < s1; e += 4) {
            float4 na0, nb0, na1, nb1, na2, nb2, na3, nb3;
            LOAD4(na0, nb0, na1, nb1, na2, nb2, na3, nb3, e + 4);   // prefetch next
            PROC4();                                                 // compute current
            ka0 = na0; kb0 = nb0; ka1 = na1; kb1 = nb1;
            ka2 = na2; kb2 = nb2; ka3 = na3; kb3 = nb3;
        }
        PROC4();
        e += 4;
    }
    for (; e < s1; ++e) {
        const float4* K4 = (const float4*)(K + (size_t)e * DKDIM);
        const float4 ka = K4[lane];
        const float4 kb = K4[64 + lane];
        float p = dot8(qa, qb, ka, kb);
        #pragma unroll
        for (int off = 32; off >= 1; off >>= 1) p += __shfl_xor(p, off, 64);
        const float nm  = fmaxf(m, p);
        const float sc  = __expf(m - nm);
        const float wgt = __expf(p - nm);
        l = l * sc + wgt;
        c0 = c0 * sc + wgt * ka.x;  c1 = c1 * sc + wgt * ka.y;
        c2 = c2 * sc + wgt * ka.z;  c3 = c3 * sc + wgt * ka.w;
        c4 = c4 * sc + wgt * kb.x;  c5 = c5 * sc + wgt * kb.y;
        c6 = c6 * sc + wgt * kb.z;  c7 = c7 * sc + wgt * kb.w;
        m = nm;
    }

    const float rin = (s1 > s0) ? (1.0f / l) : 0.0f;  // empty segment -> ctx = 0
    ushort4 oa, ob;
    oa.x = f2bf(c0 * rin); oa.y = f2bf(c1 * rin); oa.z = f2bf(c2 * rin); oa.w = f2bf(c3 * rin);
    ob.x = f2bf(c4 * rin); ob.y = f2bf(c5 * rin); ob.z = f2bf(c6 * rin); ob.w = f2bf(c7 * rin);
    ushort4* O4 = (ushort4*)(ctxb + (size_t)b * DKDIM);
    O4[lane]      = oa;
    O4[64 + lane] = ob;
}

// ---------------- Stage 2: out = ctx @ W_o + b_o via bf16 MFMA ---------------
// No LDS: fragments read directly from L2/L3-resident ctx-bf16 and Wt.
// Each wave: 64x32 output tile. 2-stage register double-buffer.
__global__ __launch_bounds__(256, 4) void proj_kernel(
    const unsigned short* __restrict__ A,   // ctx bf16, [16384][512] row-major
    const unsigned short* __restrict__ Bt,  // W_o^T bf16, [512 n][512 k]
    const float* __restrict__ bias, float* __restrict__ out)
{
    const int w = threadIdx.x >> 6, lane = threadIdx.x & 63;
    const int cpx = (int)gridDim.x >> 3;    // 1024 % 8 == 0 -> bijective
    const int bid = (blockIdx.x & 7) * cpx + (blockIdx.x >> 3);
    const int gw   = bid * 4 + w;           // 0..4095
    const int mrow = (gw >> 4) << 6;        // 256 row-tiles of 64
    const int ncol = (gw & 15) << 5;        // 16 col-tiles of 32
    const int lr = lane & 15, lg = lane >> 4;

    f32x4 acc[4][2];
    #pragma unroll
    for (int i = 0; i < 4; ++i)
        #pragma unroll
        for (int j = 0; j < 2; ++j)
            acc[i][j] = (f32x4){0.f, 0.f, 0.f, 0.f};

#define LOADK(aa, bb, kk)                                                                     \
    {                                                                                         \
        const int koff = (kk) + lg * 8;                                                       \
        _Pragma("unroll")                                                                     \
        for (int i = 0; i < 4; ++i)                                                           \
            aa[i] = *(const bf16x8*)(A + (size_t)(mrow + i * 16 + lr) * DKDIM + koff);        \
        _Pragma("unroll")                                                                     \
        for (int j = 0; j < 2; ++j)                                                           \
            bb[j] = *(const bf16x8*)(Bt + (size_t)(ncol + j * 16 + lr) * DKDIM + koff);       \
    }

#define MFMAK(aa, bb)                                                                         \
    {                                                                                         \
        _Pragma("unroll")                                                                     \
        for (int i = 0; i < 4; ++i)                                                           \
            _Pragma("unroll")                                                                 \
            for (int j = 0; j < 2; ++j)                                                       \
                acc[i][j] = __builtin_amdgcn_mfma_f32_16x16x32_bf16(aa[i], bb[j],             \
                                                                    acc[i][j], 0, 0, 0);      \
    }

    bf16x8 a0[4], b0[2], a1[4], b1[2];
    LOADK(a0, b0, 0);
    #pragma unroll
    for (int k0 = 0; k0 < DKDIM; k0 += 64) {
        LOADK(a1, b1, k0 + 32);                       // prefetch odd step
        MFMAK(a0, b0);
        if (k0 + 64 < DKDIM) LOADK(a0, b0, k0 + 64);  // prefetch next even step
        MFMAK(a1, b1);
    }

    #pragma unroll
    for (int i = 0; i < 4; ++i) {
        #pragma unroll
        for (int j = 0; j < 2; ++j) {
            const int col = ncol + j * 16 + lr;
            const float bb = bias[col];
            #pragma unroll
            for (int r = 0; r < 4; ++r) {
                const int row = mrow + i * 16 + lg * 4 + r;  // m89-verified C/D layout
                out[(size_t)row * DOUT + col] = acc[i][j][r] + bb;
            }
        }
    }
}

extern "C" void kernel_launch(void* const* d_in, const int* in_sizes, int n_in,
                              void* d_out, int out_size, void* d_ws, size_t ws_size,
                              hipStream_t stream) {
    const float* Q  = (const float*)d_in[0];
    const float* K  = (const float*)d_in[1];
    const int*   td = (const int*)d_in[2];
    const float* Wo = (const float*)d_in[3];
    const float* bo = (const float*)d_in[4];
    float* out = (float*)d_out;

    unsigned short* ctxb = (unsigned short*)d_ws;                  // 16.8 MB
    unsigned short* Wt   = ctxb + (size_t)B_SEG * DKDIM;           // + 0.5 MB
    int* starts = (int*)(Wt + (size_t)DOUT * DKDIM);               // + 64 KB

    hipLaunchKernelGGL(prep_kernel, dim3(1024 + 64), dim3(256), 0, stream, td, starts, Wo, Wt);
    hipLaunchKernelGGL(attn_kernel, dim3(B_SEG), dim3(64), 0, stream, Q, K, starts, ctxb);
    // ATTRIBUTION (this round only): proj launched 4x — idempotent, identical
    // bytes rewritten. (dur - ~173)/3 ~= proj duration.
    hipLaunchKernelGGL(proj_kernel, dim3((B_SEG / 64) * (DOUT / 32) / 4), dim3(256), 0, stream,
                       ctxb, Wt, bo, out);
    hipLaunchKernelGGL(proj_kernel, dim3((B_SEG / 64) * (DOUT / 32) / 4), dim3(256), 0, stream,
                       ctxb, Wt, bo, out);
    hipLaunchKernelGGL(proj_kernel, dim3((B_SEG / 64) * (DOUT / 32) / 4), dim3(256), 0, stream,
                       ctxb, Wt, bo, out);
    hipLaunchKernelGGL(proj_kernel, dim3((B_SEG / 64) * (DOUT / 32) / 4), dim3(256), 0, stream,
                       ctxb, Wt, bo, out);
}

// Round 7
// 147.599 us; speedup vs baseline: 2.1572x; 2.1572x over previous
//
#include <hip/hip_runtime.h>
#include <hip/hip_bf16.h>

#define B_SEG 16384
#define R_EDGE 262144
#define DKDIM 512
#define DOUT 512

typedef __attribute__((ext_vector_type(4))) float f32x4;
typedef __attribute__((ext_vector_type(8))) short bf16x8;

static __device__ __forceinline__ unsigned short f2bf(float f) {
    union { float f; unsigned int u; } v; v.f = f;
    unsigned int r = (v.u + 0x7FFFu + ((v.u >> 16) & 1u)) >> 16;
    return (unsigned short)r;
}

static __device__ __forceinline__ float dot8(const float4 qa, const float4 qb,
                                             const float4 ka, const float4 kb) {
    return qa.x * ka.x + qa.y * ka.y + qa.z * ka.z + qa.w * ka.w
         + qb.x * kb.x + qb.y * kb.y + qb.z * kb.z + qb.w * kb.w;
}

// ---------------- Stage 0: prep = starts scatter + W_o transpose (fused) -----
__global__ __launch_bounds__(256) void prep_kernel(
    const int* __restrict__ td, int* __restrict__ starts,
    const float* __restrict__ W, unsigned short* __restrict__ Wt)
{
    if (blockIdx.x < 1024) {
        const int e = blockIdx.x * 256 + threadIdx.x;
        const int cur  = td[e];
        const int prev = (e == 0) ? -1 : td[e - 1];
        for (int b = prev + 1; b <= cur; ++b) starts[b] = e;
        if (e == R_EDGE - 1)
            for (int b = cur + 1; b <= B_SEG; ++b) starts[b] = R_EDGE;
    } else {
        __shared__ unsigned short tile[64][68];
        const int bb = blockIdx.x - 1024;
        const int n0 = (bb & 7) * 64;
        const int k0 = (bb >> 3) * 64;
        const int tx = threadIdx.x & 63, g = threadIdx.x >> 6;
        #pragma unroll
        for (int dy = 0; dy < 16; ++dy) {
            const int k = g * 16 + dy;
            tile[tx][k] = f2bf(W[(size_t)(k0 + k) * DOUT + n0 + tx]);  // coalesced
        }
        __syncthreads();
        #pragma unroll
        for (int dr = 0; dr < 16; ++dr) {
            const int r = g * 16 + dr;
            Wt[(size_t)(n0 + r) * DKDIM + k0 + tx] = tile[r][tx];      // coalesced
        }
    }
}

// ---------------- Stage 1: fused segment attention ---------------------------
// ONE SEGMENT = ONE 64-THREAD BLOCK. Online softmax with defer-max (T13):
// p/m are wave-uniform, so the rescale-skip branch is divergence-free.
// Weights bounded by e^8; f32 accumulate; softmax ratio exact.
__global__ __launch_bounds__(64, 4) void attn_kernel(
    const float* __restrict__ Q, const float* __restrict__ K,
    const int* __restrict__ starts, unsigned short* __restrict__ ctxb)
{
    const int lane = threadIdx.x & 63;
    const int b = blockIdx.x;

    const int s0 = starts[b];
    const int s1 = starts[b + 1];

    const float4* Q4 = (const float4*)(Q + (size_t)b * DKDIM);
    const float4 qa = Q4[lane];
    const float4 qb = Q4[64 + lane];

    float m = -INFINITY, l = 0.0f;
    float c0 = 0.f, c1 = 0.f, c2 = 0.f, c3 = 0.f;
    float c4 = 0.f, c5 = 0.f, c6 = 0.f, c7 = 0.f;

    float4 ka0, kb0, ka1, kb1, ka2, kb2, ka3, kb3;

#define LOAD4(dst_a0, dst_b0, dst_a1, dst_b1, dst_a2, dst_b2, dst_a3, dst_b3, ee)            \
    {                                                                                        \
        const float4* K0_ = (const float4*)(K + (size_t)((ee) + 0) * DKDIM);                 \
        const float4* K1_ = (const float4*)(K + (size_t)((ee) + 1) * DKDIM);                 \
        const float4* K2_ = (const float4*)(K + (size_t)((ee) + 2) * DKDIM);                 \
        const float4* K3_ = (const float4*)(K + (size_t)((ee) + 3) * DKDIM);                 \
        dst_a0 = K0_[lane]; dst_b0 = K0_[64 + lane];                                         \
        dst_a1 = K1_[lane]; dst_b1 = K1_[64 + lane];                                         \
        dst_a2 = K2_[lane]; dst_b2 = K2_[64 + lane];                                         \
        dst_a3 = K3_[lane]; dst_b3 = K3_[64 + lane];                                         \
    }

#define PROC4()                                                                              \
    {                                                                                        \
        float p0 = dot8(qa, qb, ka0, kb0);                                                   \
        float p1 = dot8(qa, qb, ka1, kb1);                                                   \
        float p2 = dot8(qa, qb, ka2, kb2);                                                   \
        float p3 = dot8(qa, qb, ka3, kb3);                                                   \
        _Pragma("unroll")                                                                    \
        for (int off = 32; off >= 1; off >>= 1) {                                            \
            p0 += __shfl_xor(p0, off, 64);                                                   \
            p1 += __shfl_xor(p1, off, 64);                                                   \
            p2 += __shfl_xor(p2, off, 64);                                                   \
            p3 += __shfl_xor(p3, off, 64);                                                   \
        }                                                                                    \
        const float gmax = fmaxf(fmaxf(p0, p1), fmaxf(p2, p3));                              \
        if (gmax > m + 8.0f) {   /* wave-uniform branch; m=-inf first group */               \
            const float sc = __expf(m - gmax);                                               \
            l *= sc;                                                                         \
            c0 *= sc; c1 *= sc; c2 *= sc; c3 *= sc;                                          \
            c4 *= sc; c5 *= sc; c6 *= sc; c7 *= sc;                                          \
            m = gmax;                                                                        \
        }                                                                                    \
        const float w0 = __expf(p0 - m), w1 = __expf(p1 - m);                                \
        const float w2 = __expf(p2 - m), w3 = __expf(p3 - m);                                \
        l += (w0 + w1) + (w2 + w3);                                                          \
        c0 += (w0 * ka0.x + w1 * ka1.x) + (w2 * ka2.x + w3 * ka3.x);                         \
        c1 += (w0 * ka0.y + w1 * ka1.y) + (w2 * ka2.y + w3 * ka3.y);                         \
        c2 += (w0 * ka0.z + w1 * ka1.z) + (w2 * ka2.z + w3 * ka3.z);                         \
        c3 += (w0 * ka0.w + w1 * ka1.w) + (w2 * ka2.w + w3 * ka3.w);                         \
        c4 += (w0 * kb0.x + w1 * kb1.x) + (w2 * kb2.x + w3 * kb3.x);                         \
        c5 += (w0 * kb0.y + w1 * kb1.y) + (w2 * kb2.y + w3 * kb3.y);                         \
        c6 += (w0 * kb0.z + w1 * kb1.z) + (w2 * kb2.z + w3 * kb3.z);                         \
        c7 += (w0 * kb0.w + w1 * kb1.w) + (w2 * kb2.w + w3 * kb3.w);                         \
    }

    int e = s0;
    if (s1 - s0 >= 4) {
        LOAD4(ka0, kb0, ka1, kb1, ka2, kb2, ka3, kb3, e);
        for (; e + 7 < s1; e += 4) {
            float4 na0, nb0, na1, nb1, na2, nb2, na3, nb3;
            LOAD4(na0, nb0, na1, nb1, na2, nb2, na3, nb3, e + 4);   // prefetch next
            PROC4();                                                 // compute current
            ka0 = na0; kb0 = nb0; ka1 = na1; kb1 = nb1;
            ka2 = na2; kb2 = nb2; ka3 = na3; kb3 = nb3;
        }
        PROC4();
        e += 4;
    }
    for (; e < s1; ++e) {
        const float4* K4 = (const float4*)(K + (size_t)e * DKDIM);
        const float4 ka = K4[lane];
        const float4 kb = K4[64 + lane];
        float p = dot8(qa, qb, ka, kb);
        #pragma unroll
        for (int off = 32; off >= 1; off >>= 1) p += __shfl_xor(p, off, 64);
        if (p > m + 8.0f) {
            const float sc = __expf(m - p);
            l *= sc;
            c0 *= sc; c1 *= sc; c2 *= sc; c3 *= sc;
            c4 *= sc; c5 *= sc; c6 *= sc; c7 *= sc;
            m = p;
        }
        const float wgt = __expf(p - m);
        l += wgt;
        c0 += wgt * ka.x;  c1 += wgt * ka.y;
        c2 += wgt * ka.z;  c3 += wgt * ka.w;
        c4 += wgt * kb.x;  c5 += wgt * kb.y;
        c6 += wgt * kb.z;  c7 += wgt * kb.w;
    }

    const float rin = (s1 > s0) ? (1.0f / l) : 0.0f;  // empty segment -> ctx = 0
    ushort4 oa, ob;
    oa.x = f2bf(c0 * rin); oa.y = f2bf(c1 * rin); oa.z = f2bf(c2 * rin); oa.w = f2bf(c3 * rin);
    ob.x = f2bf(c4 * rin); ob.y = f2bf(c5 * rin); ob.z = f2bf(c6 * rin); ob.w = f2bf(c7 * rin);
    ushort4* O4 = (ushort4*)(ctxb + (size_t)b * DKDIM);
    O4[lane]      = oa;
    O4[64 + lane] = ob;
}

// ---------------- Stage 2: out = ctx @ W_o + b_o (m97-lite LDS GEMM) ---------
// 128x64 block tile, BK=32, 4 waves (64x32 quadrant each), double-buffered LDS
// staged via global_load_lds width=16 (bulk DMA). ds_read_b128 slot-uniform:
// 16B-slot = (lr*4+lg) mod 8 -> conflict-free. XCD-bijective m-band mapping.
#define PBM 128
#define PBN 64
#define PBK 32

#define GLOAD_LDS(gsrc, ldst)                                                                \
    __builtin_amdgcn_global_load_lds(                                                        \
        (const __attribute__((address_space(1))) void*)(gsrc),                               \
        (__attribute__((address_space(3))) void*)(ldst), 16, 0, 0)

__global__ __launch_bounds__(256, 4) void proj_kernel(
    const unsigned short* __restrict__ A,   // ctx bf16, [16384][512] row-major
    const unsigned short* __restrict__ Bt,  // W_o^T bf16, [512 n][512 k]
    const float* __restrict__ bias, float* __restrict__ out)
{
    __shared__ unsigned short ldsA[2][PBM * PBK];
    __shared__ unsigned short ldsB[2][PBN * PBK];

    const int w = threadIdx.x >> 6, lane = threadIdx.x & 63;
    // XCD-bijective: xcd x owns a contiguous band of 16 m-tiles (2 MB of A).
    const int x = (int)blockIdx.x & 7, idx = (int)blockIdx.x >> 3;  // idx 0..127
    const int tile_m = x * 16 + (idx >> 3);   // 0..127
    const int tile_n = idx & 7;               // 0..7
    const int mrow  = tile_m * PBM;
    const int ncol0 = tile_n * PBN;
    const int wr = w >> 1, wc = w & 1;
    const int lr = lane & 15, lg = lane >> 4;

    const int srow = lane >> 2;           // staging: lane's row-within-16
    const int scol = (lane & 3) * 8;      // staging: lane's k-offset (elems)

#define STAGE(buf, ks)                                                                       \
    {                                                                                        \
        const int k0_ = (ks) * PBK;                                                          \
        GLOAD_LDS(A + (size_t)(mrow + w * 32 + srow) * DKDIM + k0_ + scol,                   \
                  &ldsA[buf][(w * 32) * PBK]);                                               \
        GLOAD_LDS(A + (size_t)(mrow + w * 32 + 16 + srow) * DKDIM + k0_ + scol,              \
                  &ldsA[buf][(w * 32 + 16) * PBK]);                                          \
        GLOAD_LDS(Bt + (size_t)(ncol0 + w * 16 + srow) * DKDIM + k0_ + scol,                 \
                  &ldsB[buf][(w * 16) * PBK]);                                               \
    }

    f32x4 acc[4][2];
    #pragma unroll
    for (int i = 0; i < 4; ++i)
        #pragma unroll
        for (int j = 0; j < 2; ++j)
            acc[i][j] = (f32x4){0.f, 0.f, 0.f, 0.f};

    STAGE(0, 0);
    __syncthreads();   // drains vmcnt -> buf0 ready

    int cur = 0;
    for (int ks = 0; ks < DKDIM / PBK; ++ks) {
        if (ks + 1 < DKDIM / PBK) STAGE(cur ^ 1, ks + 1);   // DMA next while computing
        bf16x8 af[4], bfr[2];
        #pragma unroll
        for (int mq = 0; mq < 4; ++mq)
            af[mq] = *(const bf16x8*)&ldsA[cur][(wr * 64 + mq * 16 + lr) * PBK + lg * 8];
        #pragma unroll
        for (int nq = 0; nq < 2; ++nq)
            bfr[nq] = *(const bf16x8*)&ldsB[cur][(wc * 32 + nq * 16 + lr) * PBK + lg * 8];
        #pragma unroll
        for (int mq = 0; mq < 4; ++mq)
            #pragma unroll
            for (int nq = 0; nq < 2; ++nq)
                acc[mq][nq] = __builtin_amdgcn_mfma_f32_16x16x32_bf16(af[mq], bfr[nq],
                                                                      acc[mq][nq], 0, 0, 0);
        __syncthreads();   // drains vmcnt(0)+lgkmcnt -> next buf ready, reads done
        cur ^= 1;
    }

    #pragma unroll
    for (int mq = 0; mq < 4; ++mq) {
        #pragma unroll
        for (int nq = 0; nq < 2; ++nq) {
            const int col = ncol0 + wc * 32 + nq * 16 + lr;
            const float bb = bias[col];
            #pragma unroll
            for (int r = 0; r < 4; ++r) {
                const int row = mrow + wr * 64 + mq * 16 + lg * 4 + r;  // m89 C/D layout
                out[(size_t)row * DOUT + col] = acc[mq][nq][r] + bb;
            }
        }
    }
}

extern "C" void kernel_launch(void* const* d_in, const int* in_sizes, int n_in,
                              void* d_out, int out_size, void* d_ws, size_t ws_size,
                              hipStream_t stream) {
    const float* Q  = (const float*)d_in[0];
    const float* K  = (const float*)d_in[1];
    const int*   td = (const int*)d_in[2];
    const float* Wo = (const float*)d_in[3];
    const float* bo = (const float*)d_in[4];
    float* out = (float*)d_out;

    unsigned short* ctxb = (unsigned short*)d_ws;                  // 16.8 MB
    unsigned short* Wt   = ctxb + (size_t)B_SEG * DKDIM;           // + 0.5 MB
    int* starts = (int*)(Wt + (size_t)DOUT * DKDIM);               // + 64 KB

    hipLaunchKernelGGL(prep_kernel, dim3(1024 + 64), dim3(256), 0, stream, td, starts, Wo, Wt);
    hipLaunchKernelGGL(attn_kernel, dim3(B_SEG), dim3(64), 0, stream, Q, K, starts, ctxb);
    hipLaunchKernelGGL(proj_kernel, dim3((B_SEG / PBM) * (DOUT / PBN)), dim3(256), 0, stream,
                       ctxb, Wt, bo, out);
}

// Round 8
// 131.182 us; speedup vs baseline: 2.4272x; 1.1251x over previous
//
#include <hip/hip_runtime.h>
#include <hip/hip_bf16.h>

#define B_SEG 16384
#define R_EDGE 262144
#define DKDIM 512
#define DOUT 512

typedef __attribute__((ext_vector_type(4))) float f32x4;
typedef __attribute__((ext_vector_type(8))) short bf16x8;

static __device__ __forceinline__ unsigned short f2bf(float f) {
    union { float f; unsigned int u; } v; v.f = f;
    unsigned int r = (v.u + 0x7FFFu + ((v.u >> 16) & 1u)) >> 16;
    return (unsigned short)r;
}

static __device__ __forceinline__ float dot8v(const f32x4 qa, const f32x4 qb,
                                              const f32x4 ka, const f32x4 kb) {
    return qa[0] * ka[0] + qa[1] * ka[1] + qa[2] * ka[2] + qa[3] * ka[3]
         + qb[0] * kb[0] + qb[1] * kb[1] + qb[2] * kb[2] + qb[3] * kb[3];
}

// ---------------- Stage 0: starts table (parallel scatter) -------------------
__global__ __launch_bounds__(256) void starts_kernel(const int* __restrict__ td,
                                                     int* __restrict__ starts)
{
    const int e = blockIdx.x * 256 + threadIdx.x;
    const int cur  = td[e];
    const int prev = (e == 0) ? -1 : td[e - 1];
    for (int b = prev + 1; b <= cur; ++b) starts[b] = e;
    if (e == R_EDGE - 1)
        for (int b = cur + 1; b <= B_SEG; ++b) starts[b] = R_EDGE;
}

// ---------------- Stage 1: fused segment attention (+hidden W_o transpose) ---
// Blocks 0..63 (dispatched first, hidden under attn): 64x64 LDS tile transpose
// of W_o into bf16 Wt. Blocks 64..16447: one segment per 64-thread block.
// Online softmax with defer-max (wave-uniform branch). K/Q loads are
// NON-TEMPORAL: read-once streams, don't churn L2.
__global__ __launch_bounds__(64, 4) void attn_kernel(
    const float* __restrict__ Q, const float* __restrict__ K,
    const int* __restrict__ starts, unsigned short* __restrict__ ctxb,
    const float* __restrict__ W, unsigned short* __restrict__ Wt)
{
    __shared__ unsigned short tile[64][68];
    const int lane = threadIdx.x & 63;

    if (blockIdx.x < 64) {                    // W_o transpose, runs first, hidden
        const int bb = blockIdx.x;
        const int n0 = (bb & 7) * 64;
        const int k0 = (bb >> 3) * 64;
        for (int k = 0; k < 64; ++k)
            tile[lane][k] = f2bf(W[(size_t)(k0 + k) * DOUT + n0 + lane]);  // coalesced
        __syncthreads();
        for (int r = 0; r < 64; ++r)
            Wt[(size_t)(n0 + r) * DKDIM + k0 + lane] = tile[r][lane];      // coalesced
        return;
    }

    const int b = blockIdx.x - 64;
    const int s0 = starts[b];
    const int s1 = starts[b + 1];

    const f32x4* Q4 = (const f32x4*)(Q + (size_t)b * DKDIM);
    const f32x4 qa = __builtin_nontemporal_load(Q4 + lane);
    const f32x4 qb = __builtin_nontemporal_load(Q4 + 64 + lane);

    float m = -INFINITY, l = 0.0f;
    float c0 = 0.f, c1 = 0.f, c2 = 0.f, c3 = 0.f;
    float c4 = 0.f, c5 = 0.f, c6 = 0.f, c7 = 0.f;

    f32x4 ka0, kb0, ka1, kb1, ka2, kb2, ka3, kb3;

#define LOAD4(dst_a0, dst_b0, dst_a1, dst_b1, dst_a2, dst_b2, dst_a3, dst_b3, ee)            \
    {                                                                                        \
        const f32x4* K0_ = (const f32x4*)(K + (size_t)((ee) + 0) * DKDIM);                   \
        const f32x4* K1_ = (const f32x4*)(K + (size_t)((ee) + 1) * DKDIM);                   \
        const f32x4* K2_ = (const f32x4*)(K + (size_t)((ee) + 2) * DKDIM);                   \
        const f32x4* K3_ = (const f32x4*)(K + (size_t)((ee) + 3) * DKDIM);                   \
        dst_a0 = __builtin_nontemporal_load(K0_ + lane);                                     \
        dst_b0 = __builtin_nontemporal_load(K0_ + 64 + lane);                                \
        dst_a1 = __builtin_nontemporal_load(K1_ + lane);                                     \
        dst_b1 = __builtin_nontemporal_load(K1_ + 64 + lane);                                \
        dst_a2 = __builtin_nontemporal_load(K2_ + lane);                                     \
        dst_b2 = __builtin_nontemporal_load(K2_ + 64 + lane);                                \
        dst_a3 = __builtin_nontemporal_load(K3_ + lane);                                     \
        dst_b3 = __builtin_nontemporal_load(K3_ + 64 + lane);                                \
    }

#define PROC4()                                                                              \
    {                                                                                        \
        float p0 = dot8v(qa, qb, ka0, kb0);                                                  \
        float p1 = dot8v(qa, qb, ka1, kb1);                                                  \
        float p2 = dot8v(qa, qb, ka2, kb2);                                                  \
        float p3 = dot8v(qa, qb, ka3, kb3);                                                  \
        _Pragma("unroll")                                                                    \
        for (int off = 32; off >= 1; off >>= 1) {                                            \
            p0 += __shfl_xor(p0, off, 64);                                                   \
            p1 += __shfl_xor(p1, off, 64);                                                   \
            p2 += __shfl_xor(p2, off, 64);                                                   \
            p3 += __shfl_xor(p3, off, 64);                                                   \
        }                                                                                    \
        const float gmax = fmaxf(fmaxf(p0, p1), fmaxf(p2, p3));                              \
        if (gmax > m + 8.0f) {   /* wave-uniform branch; m=-inf first group */               \
            const float sc = __expf(m - gmax);                                               \
            l *= sc;                                                                         \
            c0 *= sc; c1 *= sc; c2 *= sc; c3 *= sc;                                          \
            c4 *= sc; c5 *= sc; c6 *= sc; c7 *= sc;                                          \
            m = gmax;                                                                        \
        }                                                                                    \
        const float w0 = __expf(p0 - m), w1 = __expf(p1 - m);                                \
        const float w2 = __expf(p2 - m), w3 = __expf(p3 - m);                                \
        l += (w0 + w1) + (w2 + w3);                                                          \
        c0 += (w0 * ka0[0] + w1 * ka1[0]) + (w2 * ka2[0] + w3 * ka3[0]);                     \
        c1 += (w0 * ka0[1] + w1 * ka1[1]) + (w2 * ka2[1] + w3 * ka3[1]);                     \
        c2 += (w0 * ka0[2] + w1 * ka1[2]) + (w2 * ka2[2] + w3 * ka3[2]);                     \
        c3 += (w0 * ka0[3] + w1 * ka1[3]) + (w2 * ka2[3] + w3 * ka3[3]);                     \
        c4 += (w0 * kb0[0] + w1 * kb1[0]) + (w2 * kb2[0] + w3 * kb3[0]);                     \
        c5 += (w0 * kb0[1] + w1 * kb1[1]) + (w2 * kb2[1] + w3 * kb3[1]);                     \
        c6 += (w0 * kb0[2] + w1 * kb1[2]) + (w2 * kb2[2] + w3 * kb3[2]);                     \
        c7 += (w0 * kb0[3] + w1 * kb1[3]) + (w2 * kb2[3] + w3 * kb3[3]);                     \
    }

    int e = s0;
    if (s1 - s0 >= 4) {
        LOAD4(ka0, kb0, ka1, kb1, ka2, kb2, ka3, kb3, e);
        for (; e + 7 < s1; e += 4) {
            f32x4 na0, nb0, na1, nb1, na2, nb2, na3, nb3;
            LOAD4(na0, nb0, na1, nb1, na2, nb2, na3, nb3, e + 4);   // prefetch next
            PROC4();                                                 // compute current
            ka0 = na0; kb0 = nb0; ka1 = na1; kb1 = nb1;
            ka2 = na2; kb2 = nb2; ka3 = na3; kb3 = nb3;
        }
        PROC4();
        e += 4;
    }
    for (; e < s1; ++e) {
        const f32x4* K4 = (const f32x4*)(K + (size_t)e * DKDIM);
        const f32x4 ka = __builtin_nontemporal_load(K4 + lane);
        const f32x4 kb = __builtin_nontemporal_load(K4 + 64 + lane);
        float p = dot8v(qa, qb, ka, kb);
        #pragma unroll
        for (int off = 32; off >= 1; off >>= 1) p += __shfl_xor(p, off, 64);
        if (p > m + 8.0f) {
            const float sc = __expf(m - p);
            l *= sc;
            c0 *= sc; c1 *= sc; c2 *= sc; c3 *= sc;
            c4 *= sc; c5 *= sc; c6 *= sc; c7 *= sc;
            m = p;
        }
        const float wgt = __expf(p - m);
        l += wgt;
        c0 += wgt * ka[0];  c1 += wgt * ka[1];
        c2 += wgt * ka[2];  c3 += wgt * ka[3];
        c4 += wgt * kb[0];  c5 += wgt * kb[1];
        c6 += wgt * kb[2];  c7 += wgt * kb[3];
    }

    const float rin = (s1 > s0) ? (1.0f / l) : 0.0f;  // empty segment -> ctx = 0
    ushort4 oa, ob;
    oa.x = f2bf(c0 * rin); oa.y = f2bf(c1 * rin); oa.z = f2bf(c2 * rin); oa.w = f2bf(c3 * rin);
    ob.x = f2bf(c4 * rin); ob.y = f2bf(c5 * rin); ob.z = f2bf(c6 * rin); ob.w = f2bf(c7 * rin);
    ushort4* O4 = (ushort4*)(ctxb + (size_t)b * DKDIM);
    O4[lane]      = oa;    // normal store: proj re-reads ctx soon (keep in L2)
    O4[64 + lane] = ob;
}

// ---------------- Stage 2: out = ctx @ W_o + b_o (m97-lite LDS GEMM) ---------
// 128x64 block tile, BK=32, 4 waves (64x32 quadrant each), double-buffered LDS
// staged via global_load_lds width=16. XCD-bijective m-band mapping.
// out stores are NON-TEMPORAL (write-once).
#define PBM 128
#define PBN 64
#define PBK 32

#define GLOAD_LDS(gsrc, ldst)                                                                \
    __builtin_amdgcn_global_load_lds(                                                        \
        (const __attribute__((address_space(1))) void*)(gsrc),                               \
        (__attribute__((address_space(3))) void*)(ldst), 16, 0, 0)

__global__ __launch_bounds__(256, 4) void proj_kernel(
    const unsigned short* __restrict__ A,   // ctx bf16, [16384][512] row-major
    const unsigned short* __restrict__ Bt,  // W_o^T bf16, [512 n][512 k]
    const float* __restrict__ bias, float* __restrict__ out)
{
    __shared__ unsigned short ldsA[2][PBM * PBK];
    __shared__ unsigned short ldsB[2][PBN * PBK];

    const int w = threadIdx.x >> 6, lane = threadIdx.x & 63;
    const int x = (int)blockIdx.x & 7, idx = (int)blockIdx.x >> 3;  // idx 0..127
    const int tile_m = x * 16 + (idx >> 3);   // 0..127
    const int tile_n = idx & 7;               // 0..7
    const int mrow  = tile_m * PBM;
    const int ncol0 = tile_n * PBN;
    const int wr = w >> 1, wc = w & 1;
    const int lr = lane & 15, lg = lane >> 4;

    const int srow = lane >> 2;           // staging: lane's row-within-16
    const int scol = (lane & 3) * 8;      // staging: lane's k-offset (elems)

#define STAGE(buf, ks)                                                                       \
    {                                                                                        \
        const int k0_ = (ks) * PBK;                                                          \
        GLOAD_LDS(A + (size_t)(mrow + w * 32 + srow) * DKDIM + k0_ + scol,                   \
                  &ldsA[buf][(w * 32) * PBK]);                                               \
        GLOAD_LDS(A + (size_t)(mrow + w * 32 + 16 + srow) * DKDIM + k0_ + scol,              \
                  &ldsA[buf][(w * 32 + 16) * PBK]);                                          \
        GLOAD_LDS(Bt + (size_t)(ncol0 + w * 16 + srow) * DKDIM + k0_ + scol,                 \
                  &ldsB[buf][(w * 16) * PBK]);                                               \
    }

    f32x4 acc[4][2];
    #pragma unroll
    for (int i = 0; i < 4; ++i)
        #pragma unroll
        for (int j = 0; j < 2; ++j)
            acc[i][j] = (f32x4){0.f, 0.f, 0.f, 0.f};

    STAGE(0, 0);
    __syncthreads();   // drains vmcnt -> buf0 ready

    int cur = 0;
    for (int ks = 0; ks < DKDIM / PBK; ++ks) {
        if (ks + 1 < DKDIM / PBK) STAGE(cur ^ 1, ks + 1);   // DMA next while computing
        bf16x8 af[4], bfr[2];
        #pragma unroll
        for (int mq = 0; mq < 4; ++mq)
            af[mq] = *(const bf16x8*)&ldsA[cur][(wr * 64 + mq * 16 + lr) * PBK + lg * 8];
        #pragma unroll
        for (int nq = 0; nq < 2; ++nq)
            bfr[nq] = *(const bf16x8*)&ldsB[cur][(wc * 32 + nq * 16 + lr) * PBK + lg * 8];
        #pragma unroll
        for (int mq = 0; mq < 4; ++mq)
            #pragma unroll
            for (int nq = 0; nq < 2; ++nq)
                acc[mq][nq] = __builtin_amdgcn_mfma_f32_16x16x32_bf16(af[mq], bfr[nq],
                                                                      acc[mq][nq], 0, 0, 0);
        __syncthreads();   // next buf ready, reads done
        cur ^= 1;
    }

    #pragma unroll
    for (int mq = 0; mq < 4; ++mq) {
        #pragma unroll
        for (int nq = 0; nq < 2; ++nq) {
            const int col = ncol0 + wc * 32 + nq * 16 + lr;
            const float bb = bias[col];
            #pragma unroll
            for (int r = 0; r < 4; ++r) {
                const int row = mrow + wr * 64 + mq * 16 + lg * 4 + r;  // m89 C/D layout
                __builtin_nontemporal_store(acc[mq][nq][r] + bb,
                                            &out[(size_t)row * DOUT + col]);
            }
        }
    }
}

extern "C" void kernel_launch(void* const* d_in, const int* in_sizes, int n_in,
                              void* d_out, int out_size, void* d_ws, size_t ws_size,
                              hipStream_t stream) {
    const float* Q  = (const float*)d_in[0];
    const float* K  = (const float*)d_in[1];
    const int*   td = (const int*)d_in[2];
    const float* Wo = (const float*)d_in[3];
    const float* bo = (const float*)d_in[4];
    float* out = (float*)d_out;

    unsigned short* ctxb = (unsigned short*)d_ws;                  // 16.8 MB
    unsigned short* Wt   = ctxb + (size_t)B_SEG * DKDIM;           // + 0.5 MB
    int* starts = (int*)(Wt + (size_t)DOUT * DKDIM);               // + 64 KB

    hipLaunchKernelGGL(starts_kernel, dim3(R_EDGE / 256), dim3(256), 0, stream, td, starts);
    hipLaunchKernelGGL(attn_kernel,   dim3(B_SEG + 64), dim3(64), 0, stream,
                       Q, K, starts, ctxb, Wo, Wt);
    hipLaunchKernelGGL(proj_kernel,   dim3((B_SEG / PBM) * (DOUT / PBN)), dim3(256), 0, stream,
                       ctxb, Wt, bo, out);
}

// Round 10
// 126.799 us; speedup vs baseline: 2.5111x; 1.0346x over previous
//
#include <hip/hip_runtime.h>
#include <hip/hip_bf16.h>

#define B_SEG 16384
#define R_EDGE 262144
#define DKDIM 512
#define DOUT 512

typedef __attribute__((ext_vector_type(4))) float f32x4;
typedef __attribute__((ext_vector_type(8))) short bf16x8;

static __device__ __forceinline__ unsigned short f2bf(float f) {
    union { float f; unsigned int u; } v; v.f = f;
    unsigned int r = (v.u + 0x7FFFu + ((v.u >> 16) & 1u)) >> 16;
    return (unsigned short)r;
}

static __device__ __forceinline__ float dot8v(const f32x4 qa, const f32x4 qb,
                                              const f32x4 ka, const f32x4 kb) {
    return qa[0] * ka[0] + qa[1] * ka[1] + qa[2] * ka[2] + qa[3] * ka[3]
         + qb[0] * kb[0] + qb[1] * kb[1] + qb[2] * kb[2] + qb[3] * kb[3];
}

// ---------------- Stage 0: starts table (parallel scatter) -------------------
__global__ __launch_bounds__(256) void starts_kernel(const int* __restrict__ td,
                                                     int* __restrict__ starts)
{
    const int e = blockIdx.x * 256 + threadIdx.x;
    const int cur  = td[e];
    const int prev = (e == 0) ? -1 : td[e - 1];
    for (int b = prev + 1; b <= cur; ++b) starts[b] = e;
    if (e == R_EDGE - 1)
        for (int b = cur + 1; b <= B_SEG; ++b) starts[b] = R_EDGE;
}

// ---------------- Stage 1: fused segment attention (+hidden W_o transpose) ---
// Blocks 0..63 (dispatched first, hidden under attn): 64x64 LDS tile transpose
// of W_o into bf16 Wt. Blocks 64..16447: one segment per 64-thread block.
// Online softmax with defer-max (wave-uniform branch). K/Q loads are
// NON-TEMPORAL: read-once streams, don't churn L2.
__global__ __launch_bounds__(64, 4) void attn_kernel(
    const float* __restrict__ Q, const float* __restrict__ K,
    const int* __restrict__ starts, unsigned short* __restrict__ ctxb,
    const float* __restrict__ W, unsigned short* __restrict__ Wt)
{
    __shared__ unsigned short tile[64][68];
    const int lane = threadIdx.x & 63;

    if (blockIdx.x < 64) {                    // W_o transpose, runs first, hidden
        const int bb = blockIdx.x;
        const int n0 = (bb & 7) * 64;
        const int k0 = (bb >> 3) * 64;
        for (int k = 0; k < 64; ++k)
            tile[lane][k] = f2bf(W[(size_t)(k0 + k) * DOUT + n0 + lane]);  // coalesced
        __syncthreads();
        for (int r = 0; r < 64; ++r)
            Wt[(size_t)(n0 + r) * DKDIM + k0 + lane] = tile[r][lane];      // coalesced
        return;
    }

    const int b = blockIdx.x - 64;
    const int s0 = starts[b];
    const int s1 = starts[b + 1];

    const f32x4* Q4 = (const f32x4*)(Q + (size_t)b * DKDIM);
    const f32x4 qa = __builtin_nontemporal_load(Q4 + lane);
    const f32x4 qb = __builtin_nontemporal_load(Q4 + 64 + lane);

    float m = -INFINITY, l = 0.0f;
    float c0 = 0.f, c1 = 0.f, c2 = 0.f, c3 = 0.f;
    float c4 = 0.f, c5 = 0.f, c6 = 0.f, c7 = 0.f;

    f32x4 ka0, kb0, ka1, kb1, ka2, kb2, ka3, kb3;

#define LOAD4(dst_a0, dst_b0, dst_a1, dst_b1, dst_a2, dst_b2, dst_a3, dst_b3, ee)            \
    {                                                                                        \
        const f32x4* K0_ = (const f32x4*)(K + (size_t)((ee) + 0) * DKDIM);                   \
        const f32x4* K1_ = (const f32x4*)(K + (size_t)((ee) + 1) * DKDIM);                   \
        const f32x4* K2_ = (const f32x4*)(K + (size_t)((ee) + 2) * DKDIM);                   \
        const f32x4* K3_ = (const f32x4*)(K + (size_t)((ee) + 3) * DKDIM);                   \
        dst_a0 = __builtin_nontemporal_load(K0_ + lane);                                     \
        dst_b0 = __builtin_nontemporal_load(K0_ + 64 + lane);                                \
        dst_a1 = __builtin_nontemporal_load(K1_ + lane);                                     \
        dst_b1 = __builtin_nontemporal_load(K1_ + 64 + lane);                                \
        dst_a2 = __builtin_nontemporal_load(K2_ + lane);                                     \
        dst_b2 = __builtin_nontemporal_load(K2_ + 64 + lane);                                \
        dst_a3 = __builtin_nontemporal_load(K3_ + lane);                                     \
        dst_b3 = __builtin_nontemporal_load(K3_ + 64 + lane);                                \
    }

#define PROC4()                                                                              \
    {                                                                                        \
        float p0 = dot8v(qa, qb, ka0, kb0);                                                  \
        float p1 = dot8v(qa, qb, ka1, kb1);                                                  \
        float p2 = dot8v(qa, qb, ka2, kb2);                                                  \
        float p3 = dot8v(qa, qb, ka3, kb3);                                                  \
        _Pragma("unroll")                                                                    \
        for (int off = 32; off >= 1; off >>= 1) {                                            \
            p0 += __shfl_xor(p0, off, 64);                                                   \
            p1 += __shfl_xor(p1, off, 64);                                                   \
            p2 += __shfl_xor(p2, off, 64);                                                   \
            p3 += __shfl_xor(p3, off, 64);                                                   \
        }                                                                                    \
        const float gmax = fmaxf(fmaxf(p0, p1), fmaxf(p2, p3));                              \
        if (gmax > m + 8.0f) {   /* wave-uniform branch; m=-inf first group */               \
            const float sc = __expf(m - gmax);                                               \
            l *= sc;                                                                         \
            c0 *= sc; c1 *= sc; c2 *= sc; c3 *= sc;                                          \
            c4 *= sc; c5 *= sc; c6 *= sc; c7 *= sc;                                          \
            m = gmax;                                                                        \
        }                                                                                    \
        const float w0 = __expf(p0 - m), w1 = __expf(p1 - m);                                \
        const float w2 = __expf(p2 - m), w3 = __expf(p3 - m);                                \
        l += (w0 + w1) + (w2 + w3);                                                          \
        c0 += (w0 * ka0[0] + w1 * ka1[0]) + (w2 * ka2[0] + w3 * ka3[0]);                     \
        c1 += (w0 * ka0[1] + w1 * ka1[1]) + (w2 * ka2[1] + w3 * ka3[1]);                     \
        c2 += (w0 * ka0[2] + w1 * ka1[2]) + (w2 * ka2[2] + w3 * ka3[2]);                     \
        c3 += (w0 * ka0[3] + w1 * ka1[3]) + (w2 * ka2[3] + w3 * ka3[3]);                     \
        c4 += (w0 * kb0[0] + w1 * kb1[0]) + (w2 * kb2[0] + w3 * kb3[0]);                     \
        c5 += (w0 * kb0[1] + w1 * kb1[1]) + (w2 * kb2[1] + w3 * kb3[1]);                     \
        c6 += (w0 * kb0[2] + w1 * kb1[2]) + (w2 * kb2[2] + w3 * kb3[2]);                     \
        c7 += (w0 * kb0[3] + w1 * kb1[3]) + (w2 * kb2[3] + w3 * kb3[3]);                     \
    }

    int e = s0;
    if (s1 - s0 >= 4) {
        LOAD4(ka0, kb0, ka1, kb1, ka2, kb2, ka3, kb3, e);
        for (; e + 7 < s1; e += 4) {
            f32x4 na0, nb0, na1, nb1, na2, nb2, na3, nb3;
            LOAD4(na0, nb0, na1, nb1, na2, nb2, na3, nb3, e + 4);   // prefetch next
            PROC4();                                                 // compute current
            ka0 = na0; kb0 = nb0; ka1 = na1; kb1 = nb1;
            ka2 = na2; kb2 = nb2; ka3 = na3; kb3 = nb3;
        }
        PROC4();
        e += 4;
    }
    for (; e < s1; ++e) {
        const f32x4* K4 = (const f32x4*)(K + (size_t)e * DKDIM);
        const f32x4 ka = __builtin_nontemporal_load(K4 + lane);
        const f32x4 kb = __builtin_nontemporal_load(K4 + 64 + lane);
        float p = dot8v(qa, qb, ka, kb);
        #pragma unroll
        for (int off = 32; off >= 1; off >>= 1) p += __shfl_xor(p, off, 64);
        if (p > m + 8.0f) {
            const float sc = __expf(m - p);
            l *= sc;
            c0 *= sc; c1 *= sc; c2 *= sc; c3 *= sc;
            c4 *= sc; c5 *= sc; c6 *= sc; c7 *= sc;
            m = p;
        }
        const float wgt = __expf(p - m);
        l += wgt;
        c0 += wgt * ka[0];  c1 += wgt * ka[1];
        c2 += wgt * ka[2];  c3 += wgt * ka[3];
        c4 += wgt * kb[0];  c5 += wgt * kb[1];
        c6 += wgt * kb[2];  c7 += wgt * kb[3];
    }

    const float rin = (s1 > s0) ? (1.0f / l) : 0.0f;  // empty segment -> ctx = 0
    ushort4 oa, ob;
    oa.x = f2bf(c0 * rin); oa.y = f2bf(c1 * rin); oa.z = f2bf(c2 * rin); oa.w = f2bf(c3 * rin);
    ob.x = f2bf(c4 * rin); ob.y = f2bf(c5 * rin); ob.z = f2bf(c6 * rin); ob.w = f2bf(c7 * rin);
    ushort4* O4 = (ushort4*)(ctxb + (size_t)b * DKDIM);
    O4[lane]      = oa;    // normal store: proj re-reads ctx soon (keep in L2)
    O4[64 + lane] = ob;
}

// ---------------- Stage 2: out = ctx @ W_o + b_o (128x128, BK=64, swizzled) --
// 8 waves / 512 THREADS (r9 bug: was launched with 256), each wave a 64x32
// quadrant. LDS rows are 128B (8 x 16B slots); XOR-swizzle slot ^= (row&7)
// applied BOTH sides (rule #21): staging pre-swizzles the per-lane GLOBAL
// source (LDS dest linear, as global_load_lds requires) and ds_reads apply
// the same involution -> rows r, r+8 alias each slot = 2 lanes/bank (free).
// A re-read 4x (was 8x). XCD-bijective m-bands. out stores NON-TEMPORAL.
#define PBM 128
#define PBN 128
#define PBK 64

#define GLOAD_LDS(gsrc, ldst)                                                                \
    __builtin_amdgcn_global_load_lds(                                                        \
        (const __attribute__((address_space(1))) void*)(gsrc),                               \
        (__attribute__((address_space(3))) void*)(ldst), 16, 0, 0)

__global__ __launch_bounds__(512, 4) void proj_kernel(
    const unsigned short* __restrict__ A,   // ctx bf16, [16384][512] row-major
    const unsigned short* __restrict__ Bt,  // W_o^T bf16, [512 n][512 k]
    const float* __restrict__ bias, float* __restrict__ out)
{
    __shared__ unsigned short ldsA[2][PBM * PBK];   // 16 KB per buf
    __shared__ unsigned short ldsB[2][PBN * PBK];   // 16 KB per buf

    const int w = threadIdx.x >> 6, lane = threadIdx.x & 63;
    // XCD-bijective: 512 blocks = 8 XCDs x 64; each XCD a 16-tile m-band.
    const int x = (int)blockIdx.x & 7, idx = (int)blockIdx.x >> 3;  // idx 0..63
    const int tile_m = x * 16 + (idx >> 2);   // 0..127
    const int tile_n = idx & 3;               // 0..3
    const int mrow  = tile_m * PBM;
    const int ncol0 = tile_n * PBN;
    const int wr = w >> 2, wc = w & 3;        // wave quadrant: 2m x 4n
    const int lr = lane & 15, lg = lane >> 4;

    // staging: 8 lanes per 128B row; source slot pre-swizzled by row&7
    const int srow = lane >> 3;                         // row-within-8 (== r&7)
    const int scol = ((lane & 7) ^ srow) * 8;           // swizzled k-offset (elems)

#define STAGE(buf, ks)                                                                       \
    {                                                                                        \
        const int k0_ = (ks) * PBK;                                                          \
        GLOAD_LDS(A + (size_t)(mrow + w * 16 + srow) * DKDIM + k0_ + scol,                   \
                  &ldsA[buf][(w * 16) * PBK]);                                               \
        GLOAD_LDS(A + (size_t)(mrow + w * 16 + 8 + srow) * DKDIM + k0_ + scol,               \
                  &ldsA[buf][(w * 16 + 8) * PBK]);                                           \
        GLOAD_LDS(Bt + (size_t)(ncol0 + w * 16 + srow) * DKDIM + k0_ + scol,                 \
                  &ldsB[buf][(w * 16) * PBK]);                                               \
        GLOAD_LDS(Bt + (size_t)(ncol0 + w * 16 + 8 + srow) * DKDIM + k0_ + scol,             \
                  &ldsB[buf][(w * 16 + 8) * PBK]);                                           \
    }

    f32x4 acc[4][2];
    #pragma unroll
    for (int i = 0; i < 4; ++i)
        #pragma unroll
        for (int j = 0; j < 2; ++j)
            acc[i][j] = (f32x4){0.f, 0.f, 0.f, 0.f};

    STAGE(0, 0);
    __syncthreads();   // drains vmcnt -> buf0 ready

    int cur = 0;
    for (int ks = 0; ks < DKDIM / PBK; ++ks) {          // 8 K-steps
        if (ks + 1 < DKDIM / PBK) STAGE(cur ^ 1, ks + 1);   // DMA next while computing
        bf16x8 af[4][2], bfr[2][2];
        #pragma unroll
        for (int kk = 0; kk < 2; ++kk) {
            #pragma unroll
            for (int mq = 0; mq < 4; ++mq) {
                const int ra = wr * 64 + mq * 16 + lr;
                af[mq][kk] = *(const bf16x8*)
                    &ldsA[cur][ra * PBK + (((kk << 2) | lg) ^ (ra & 7)) * 8];
            }
            #pragma unroll
            for (int nq = 0; nq < 2; ++nq) {
                const int rb = wc * 32 + nq * 16 + lr;
                bfr[nq][kk] = *(const bf16x8*)
                    &ldsB[cur][rb * PBK + (((kk << 2) | lg) ^ (rb & 7)) * 8];
            }
        }
        #pragma unroll
        for (int kk = 0; kk < 2; ++kk)
            #pragma unroll
            for (int mq = 0; mq < 4; ++mq)
                #pragma unroll
                for (int nq = 0; nq < 2; ++nq)
                    acc[mq][nq] = __builtin_amdgcn_mfma_f32_16x16x32_bf16(
                        af[mq][kk], bfr[nq][kk], acc[mq][nq], 0, 0, 0);
        __syncthreads();   // next buf ready, reads done
        cur ^= 1;
    }

    #pragma unroll
    for (int mq = 0; mq < 4; ++mq) {
        #pragma unroll
        for (int nq = 0; nq < 2; ++nq) {
            const int col = ncol0 + wc * 32 + nq * 16 + lr;
            const float bb = bias[col];
            #pragma unroll
            for (int r = 0; r < 4; ++r) {
                const int row = mrow + wr * 64 + mq * 16 + lg * 4 + r;  // m89 C/D layout
                __builtin_nontemporal_store(acc[mq][nq][r] + bb,
                                            &out[(size_t)row * DOUT + col]);
            }
        }
    }
}

extern "C" void kernel_launch(void* const* d_in, const int* in_sizes, int n_in,
                              void* d_out, int out_size, void* d_ws, size_t ws_size,
                              hipStream_t stream) {
    const float* Q  = (const float*)d_in[0];
    const float* K  = (const float*)d_in[1];
    const int*   td = (const int*)d_in[2];
    const float* Wo = (const float*)d_in[3];
    const float* bo = (const float*)d_in[4];
    float* out = (float*)d_out;

    unsigned short* ctxb = (unsigned short*)d_ws;                  // 16.8 MB
    unsigned short* Wt   = ctxb + (size_t)B_SEG * DKDIM;           // + 0.5 MB
    int* starts = (int*)(Wt + (size_t)DOUT * DKDIM);               // + 64 KB

    hipLaunchKernelGGL(starts_kernel, dim3(R_EDGE / 256), dim3(256), 0, stream, td, starts);
    hipLaunchKernelGGL(attn_kernel,   dim3(B_SEG + 64), dim3(64), 0, stream,
                       Q, K, starts, ctxb, Wo, Wt);
    hipLaunchKernelGGL(proj_kernel,   dim3((B_SEG / PBM) * (DOUT / PBN)), dim3(512), 0, stream,
                       ctxb, Wt, bo, out);
}

// Round 11
// 123.978 us; speedup vs baseline: 2.5682x; 1.0227x over previous
//
#include <hip/hip_runtime.h>
#include <hip/hip_bf16.h>

#define B_SEG 16384
#define R_EDGE 262144
#define DKDIM 512
#define DOUT 512

typedef __attribute__((ext_vector_type(4))) float f32x4;
typedef __attribute__((ext_vector_type(8))) short bf16x8;

static __device__ __forceinline__ unsigned short f2bf(float f) {
    union { float f; unsigned int u; } v; v.f = f;
    unsigned int r = (v.u + 0x7FFFu + ((v.u >> 16) & 1u)) >> 16;
    return (unsigned short)r;
}

static __device__ __forceinline__ float dot8v(const f32x4 qa, const f32x4 qb,
                                              const f32x4 ka, const f32x4 kb) {
    return qa[0] * ka[0] + qa[1] * ka[1] + qa[2] * ka[2] + qa[3] * ka[3]
         + qb[0] * kb[0] + qb[1] * kb[1] + qb[2] * kb[2] + qb[3] * kb[3];
}

// ---------------- Stage 1: fused segment attention (+hidden W_o transpose) ---
// Blocks 0..63 (dispatched first, hidden under attn): 64x64 LDS tile transpose
// of W_o into bf16 Wt. Blocks 64..16447: one segment per 64-thread block.
// Segment bounds via IN-KERNEL wave-parallel lower_bound (3 ballot rounds,
// 262144->4096->64->exact; all blocks share probe positions -> L1/L2-hot) —
// no separate starts kernel. Online softmax with defer-max. K/Q loads
// NON-TEMPORAL (read-once streams).
__global__ __launch_bounds__(64, 6) void attn_kernel(
    const float* __restrict__ Q, const float* __restrict__ K,
    const int* __restrict__ td, unsigned short* __restrict__ ctxb,
    const float* __restrict__ W, unsigned short* __restrict__ Wt)
{
    __shared__ unsigned short tile[64][68];
    const int lane = threadIdx.x & 63;

    if (blockIdx.x < 64) {                    // W_o transpose, runs first, hidden
        const int bb = blockIdx.x;
        const int n0 = (bb & 7) * 64;
        const int k0 = (bb >> 3) * 64;
        for (int k = 0; k < 64; ++k)
            tile[lane][k] = f2bf(W[(size_t)(k0 + k) * DOUT + n0 + lane]);  // coalesced
        __syncthreads();
        for (int r = 0; r < 64; ++r)
            Wt[(size_t)(n0 + r) * DKDIM + k0 + lane] = tile[r][lane];      // coalesced
        return;
    }

    const int b = blockIdx.x - 64;

    // Dual wave-parallel lower_bound(td, b) / lower_bound(td, b+1).
    // Invariant: lb in [lo, lo+range]; probes lo+i*S keep prefix property.
    int loA = 0, loB = 0;
    #pragma unroll
    for (int S = 4096; S >= 1; S /= 64) {     // 4096, 64, 1
        const int va = td[loA + lane * S];
        const int vb = td[loB + lane * S];
        const int cA = __popcll(__ballot(va < b));
        const int cB = __popcll(__ballot(vb < b + 1));
        if (S > 1) {
            loA += (cA ? cA - 1 : 0) * S;
            loB += (cB ? cB - 1 : 0) * S;
        } else {
            loA += cA;
            loB += cB;
        }
    }
    const int s0 = loA;
    const int s1 = loB;

    const f32x4* Q4 = (const f32x4*)(Q + (size_t)b * DKDIM);
    const f32x4 qa = __builtin_nontemporal_load(Q4 + lane);
    const f32x4 qb = __builtin_nontemporal_load(Q4 + 64 + lane);

    float m = -INFINITY, l = 0.0f;
    float c0 = 0.f, c1 = 0.f, c2 = 0.f, c3 = 0.f;
    float c4 = 0.f, c5 = 0.f, c6 = 0.f, c7 = 0.f;

    f32x4 ka0, kb0, ka1, kb1, ka2, kb2, ka3, kb3;

#define LOAD4(dst_a0, dst_b0, dst_a1, dst_b1, dst_a2, dst_b2, dst_a3, dst_b3, ee)            \
    {                                                                                        \
        const f32x4* K0_ = (const f32x4*)(K + (size_t)((ee) + 0) * DKDIM);                   \
        const f32x4* K1_ = (const f32x4*)(K + (size_t)((ee) + 1) * DKDIM);                   \
        const f32x4* K2_ = (const f32x4*)(K + (size_t)((ee) + 2) * DKDIM);                   \
        const f32x4* K3_ = (const f32x4*)(K + (size_t)((ee) + 3) * DKDIM);                   \
        dst_a0 = __builtin_nontemporal_load(K0_ + lane);                                     \
        dst_b0 = __builtin_nontemporal_load(K0_ + 64 + lane);                                \
        dst_a1 = __builtin_nontemporal_load(K1_ + lane);                                     \
        dst_b1 = __builtin_nontemporal_load(K1_ + 64 + lane);                                \
        dst_a2 = __builtin_nontemporal_load(K2_ + lane);                                     \
        dst_b2 = __builtin_nontemporal_load(K2_ + 64 + lane);                                \
        dst_a3 = __builtin_nontemporal_load(K3_ + lane);                                     \
        dst_b3 = __builtin_nontemporal_load(K3_ + 64 + lane);                                \
    }

#define PROC4()                                                                              \
    {                                                                                        \
        float p0 = dot8v(qa, qb, ka0, kb0);                                                  \
        float p1 = dot8v(qa, qb, ka1, kb1);                                                  \
        float p2 = dot8v(qa, qb, ka2, kb2);                                                  \
        float p3 = dot8v(qa, qb, ka3, kb3);                                                  \
        _Pragma("unroll")                                                                    \
        for (int off = 32; off >= 1; off >>= 1) {                                            \
            p0 += __shfl_xor(p0, off, 64);                                                   \
            p1 += __shfl_xor(p1, off, 64);                                                   \
            p2 += __shfl_xor(p2, off, 64);                                                   \
            p3 += __shfl_xor(p3, off, 64);                                                   \
        }                                                                                    \
        const float gmax = fmaxf(fmaxf(p0, p1), fmaxf(p2, p3));                              \
        if (gmax > m + 8.0f) {   /* wave-uniform branch; m=-inf first group */               \
            const float sc = __expf(m - gmax);                                               \
            l *= sc;                                                                         \
            c0 *= sc; c1 *= sc; c2 *= sc; c3 *= sc;                                          \
            c4 *= sc; c5 *= sc; c6 *= sc; c7 *= sc;                                          \
            m = gmax;                                                                        \
        }                                                                                    \
        const float w0 = __expf(p0 - m), w1 = __expf(p1 - m);                                \
        const float w2 = __expf(p2 - m), w3 = __expf(p3 - m);                                \
        l += (w0 + w1) + (w2 + w3);                                                          \
        c0 += (w0 * ka0[0] + w1 * ka1[0]) + (w2 * ka2[0] + w3 * ka3[0]);                     \
        c1 += (w0 * ka0[1] + w1 * ka1[1]) + (w2 * ka2[1] + w3 * ka3[1]);                     \
        c2 += (w0 * ka0[2] + w1 * ka1[2]) + (w2 * ka2[2] + w3 * ka3[2]);                     \
        c3 += (w0 * ka0[3] + w1 * ka1[3]) + (w2 * ka2[3] + w3 * ka3[3]);                     \
        c4 += (w0 * kb0[0] + w1 * kb1[0]) + (w2 * kb2[0] + w3 * kb3[0]);                     \
        c5 += (w0 * kb0[1] + w1 * kb1[1]) + (w2 * kb2[1] + w3 * kb3[1]);                     \
        c6 += (w0 * kb0[2] + w1 * kb1[2]) + (w2 * kb2[2] + w3 * kb3[2]);                     \
        c7 += (w0 * kb0[3] + w1 * kb1[3]) + (w2 * kb2[3] + w3 * kb3[3]);                     \
    }

    int e = s0;
    if (s1 - s0 >= 4) {
        LOAD4(ka0, kb0, ka1, kb1, ka2, kb2, ka3, kb3, e);
        for (; e + 7 < s1; e += 4) {
            f32x4 na0, nb0, na1, nb1, na2, nb2, na3, nb3;
            LOAD4(na0, nb0, na1, nb1, na2, nb2, na3, nb3, e + 4);   // prefetch next
            PROC4();                                                 // compute current
            ka0 = na0; kb0 = nb0; ka1 = na1; kb1 = nb1;
            ka2 = na2; kb2 = nb2; ka3 = na3; kb3 = nb3;
        }
        PROC4();
        e += 4;
    }
    for (; e < s1; ++e) {
        const f32x4* K4 = (const f32x4*)(K + (size_t)e * DKDIM);
        const f32x4 ka = __builtin_nontemporal_load(K4 + lane);
        const f32x4 kb = __builtin_nontemporal_load(K4 + 64 + lane);
        float p = dot8v(qa, qb, ka, kb);
        #pragma unroll
        for (int off = 32; off >= 1; off >>= 1) p += __shfl_xor(p, off, 64);
        if (p > m + 8.0f) {
            const float sc = __expf(m - p);
            l *= sc;
            c0 *= sc; c1 *= sc; c2 *= sc; c3 *= sc;
            c4 *= sc; c5 *= sc; c6 *= sc; c7 *= sc;
            m = p;
        }
        const float wgt = __expf(p - m);
        l += wgt;
        c0 += wgt * ka[0];  c1 += wgt * ka[1];
        c2 += wgt * ka[2];  c3 += wgt * ka[3];
        c4 += wgt * kb[0];  c5 += wgt * kb[1];
        c6 += wgt * kb[2];  c7 += wgt * kb[3];
    }

    const float rin = (s1 > s0) ? (1.0f / l) : 0.0f;  // empty segment -> ctx = 0
    ushort4 oa, ob;
    oa.x = f2bf(c0 * rin); oa.y = f2bf(c1 * rin); oa.z = f2bf(c2 * rin); oa.w = f2bf(c3 * rin);
    ob.x = f2bf(c4 * rin); ob.y = f2bf(c5 * rin); ob.z = f2bf(c6 * rin); ob.w = f2bf(c7 * rin);
    ushort4* O4 = (ushort4*)(ctxb + (size_t)b * DKDIM);
    O4[lane]      = oa;    // normal store: proj re-reads ctx soon (keep in L2)
    O4[64 + lane] = ob;
}

// ---------------- Stage 2: out = ctx @ W_o + b_o (128x128, BK=64, swizzled) --
// 8 waves / 512 threads, each wave a 64x32 quadrant. LDS rows are 128B (8 x
// 16B slots); XOR-swizzle slot ^= (row&7) applied BOTH sides (rule #21):
// staging pre-swizzles the per-lane GLOBAL source (LDS dest linear, as
// global_load_lds requires) and ds_reads apply the same involution -> rows
// r, r+8 alias each slot = 2 lanes/bank (free). A re-read 4x. XCD-bijective
// m-bands. out stores NON-TEMPORAL.
#define PBM 128
#define PBN 128
#define PBK 64

#define GLOAD_LDS(gsrc, ldst)                                                                \
    __builtin_amdgcn_global_load_lds(                                                        \
        (const __attribute__((address_space(1))) void*)(gsrc),                               \
        (__attribute__((address_space(3))) void*)(ldst), 16, 0, 0)

__global__ __launch_bounds__(512, 4) void proj_kernel(
    const unsigned short* __restrict__ A,   // ctx bf16, [16384][512] row-major
    const unsigned short* __restrict__ Bt,  // W_o^T bf16, [512 n][512 k]
    const float* __restrict__ bias, float* __restrict__ out)
{
    __shared__ unsigned short ldsA[2][PBM * PBK];   // 16 KB per buf
    __shared__ unsigned short ldsB[2][PBN * PBK];   // 16 KB per buf

    const int w = threadIdx.x >> 6, lane = threadIdx.x & 63;
    // XCD-bijective: 512 blocks = 8 XCDs x 64; each XCD a 16-tile m-band.
    const int x = (int)blockIdx.x & 7, idx = (int)blockIdx.x >> 3;  // idx 0..63
    const int tile_m = x * 16 + (idx >> 2);   // 0..127
    const int tile_n = idx & 3;               // 0..3
    const int mrow  = tile_m * PBM;
    const int ncol0 = tile_n * PBN;
    const int wr = w >> 2, wc = w & 3;        // wave quadrant: 2m x 4n
    const int lr = lane & 15, lg = lane >> 4;

    // staging: 8 lanes per 128B row; source slot pre-swizzled by row&7
    const int srow = lane >> 3;                         // row-within-8 (== r&7)
    const int scol = ((lane & 7) ^ srow) * 8;           // swizzled k-offset (elems)

#define STAGE(buf, ks)                                                                       \
    {                                                                                        \
        const int k0_ = (ks) * PBK;                                                          \
        GLOAD_LDS(A + (size_t)(mrow + w * 16 + srow) * DKDIM + k0_ + scol,                   \
                  &ldsA[buf][(w * 16) * PBK]);                                               \
        GLOAD_LDS(A + (size_t)(mrow + w * 16 + 8 + srow) * DKDIM + k0_ + scol,               \
                  &ldsA[buf][(w * 16 + 8) * PBK]);                                           \
        GLOAD_LDS(Bt + (size_t)(ncol0 + w * 16 + srow) * DKDIM + k0_ + scol,                 \
                  &ldsB[buf][(w * 16) * PBK]);                                               \
        GLOAD_LDS(Bt + (size_t)(ncol0 + w * 16 + 8 + srow) * DKDIM + k0_ + scol,             \
                  &ldsB[buf][(w * 16 + 8) * PBK]);                                           \
    }

    f32x4 acc[4][2];
    #pragma unroll
    for (int i = 0; i < 4; ++i)
        #pragma unroll
        for (int j = 0; j < 2; ++j)
            acc[i][j] = (f32x4){0.f, 0.f, 0.f, 0.f};

    STAGE(0, 0);
    __syncthreads();   // drains vmcnt -> buf0 ready

    int cur = 0;
    for (int ks = 0; ks < DKDIM / PBK; ++ks) {          // 8 K-steps
        if (ks + 1 < DKDIM / PBK) STAGE(cur ^ 1, ks + 1);   // DMA next while computing
        bf16x8 af[4][2], bfr[2][2];
        #pragma unroll
        for (int kk = 0; kk < 2; ++kk) {
            #pragma unroll
            for (int mq = 0; mq < 4; ++mq) {
                const int ra = wr * 64 + mq * 16 + lr;
                af[mq][kk] = *(const bf16x8*)
                    &ldsA[cur][ra * PBK + (((kk << 2) | lg) ^ (ra & 7)) * 8];
            }
            #pragma unroll
            for (int nq = 0; nq < 2; ++nq) {
                const int rb = wc * 32 + nq * 16 + lr;
                bfr[nq][kk] = *(const bf16x8*)
                    &ldsB[cur][rb * PBK + (((kk << 2) | lg) ^ (rb & 7)) * 8];
            }
        }
        #pragma unroll
        for (int kk = 0; kk < 2; ++kk)
            #pragma unroll
            for (int mq = 0; mq < 4; ++mq)
                #pragma unroll
                for (int nq = 0; nq < 2; ++nq)
                    acc[mq][nq] = __builtin_amdgcn_mfma_f32_16x16x32_bf16(
                        af[mq][kk], bfr[nq][kk], acc[mq][nq], 0, 0, 0);
        __syncthreads();   // next buf ready, reads done
        cur ^= 1;
    }

    #pragma unroll
    for (int mq = 0; mq < 4; ++mq) {
        #pragma unroll
        for (int nq = 0; nq < 2; ++nq) {
            const int col = ncol0 + wc * 32 + nq * 16 + lr;
            const float bb = bias[col];
            #pragma unroll
            for (int r = 0; r < 4; ++r) {
                const int row = mrow + wr * 64 + mq * 16 + lg * 4 + r;  // m89 C/D layout
                __builtin_nontemporal_store(acc[mq][nq][r] + bb,
                                            &out[(size_t)row * DOUT + col]);
            }
        }
    }
}

extern "C" void kernel_launch(void* const* d_in, const int* in_sizes, int n_in,
                              void* d_out, int out_size, void* d_ws, size_t ws_size,
                              hipStream_t stream) {
    const float* Q  = (const float*)d_in[0];
    const float* K  = (const float*)d_in[1];
    const int*   td = (const int*)d_in[2];
    const float* Wo = (const float*)d_in[3];
    const float* bo = (const float*)d_in[4];
    float* out = (float*)d_out;

    unsigned short* ctxb = (unsigned short*)d_ws;                  // 16.8 MB
    unsigned short* Wt   = ctxb + (size_t)B_SEG * DKDIM;           // + 0.5 MB

    hipLaunchKernelGGL(attn_kernel, dim3(B_SEG + 64), dim3(64), 0, stream,
                       Q, K, td, ctxb, Wo, Wt);
    hipLaunchKernelGGL(proj_kernel, dim3((B_SEG / PBM) * (DOUT / PBN)), dim3(512), 0, stream,
                       ctxb, Wt, bo, out);
}